// Round 1
// baseline (1092.406 us; speedup 1.0000x reference)
//
#include <hip/hip_runtime.h>

// ---------------- CSR construction ----------------

__global__ __launch_bounds__(256) void k_hist(const int* __restrict__ dst,
                                              int* __restrict__ counts, int E) {
  int e = blockIdx.x * 256 + threadIdx.x;
  if (e < E) atomicAdd(&counts[dst[e]], 1);
}

__global__ __launch_bounds__(256) void k_dinv(const int* __restrict__ counts,
                                              float* __restrict__ dinv, int N) {
  int i = blockIdx.x * 256 + threadIdx.x;
  if (i < N) dinv[i] = rsqrtf((float)(counts[i] + 1));  // +1 = self loop
}

__global__ __launch_bounds__(1024) void k_scan1(const int* __restrict__ counts,
                                                int* __restrict__ excl,
                                                int* __restrict__ blksum, int n) {
  __shared__ int s[1024];
  int tid = threadIdx.x;
  int gid = blockIdx.x * 1024 + tid;
  int v = (gid < n) ? counts[gid] : 0;
  s[tid] = v;
  __syncthreads();
  for (int off = 1; off < 1024; off <<= 1) {
    int t = (tid >= off) ? s[tid - off] : 0;
    __syncthreads();
    s[tid] += t;
    __syncthreads();
  }
  if (gid < n) excl[gid] = s[tid] - v;  // exclusive
  if (tid == 1023) blksum[blockIdx.x] = s[1023];
}

__global__ void k_scan2(int* blksum, int nb) {
  if (threadIdx.x == 0) {
    int run = 0;
    for (int i = 0; i < nb; i++) { int v = blksum[i]; blksum[i] = run; run += v; }
  }
}

__global__ __launch_bounds__(1024) void k_scan3(int* __restrict__ excl,
                                                const int* __restrict__ blksum,
                                                int n, int total) {
  int gid = blockIdx.x * 1024 + threadIdx.x;
  if (gid < n) excl[gid] += blksum[blockIdx.x];
  if (gid == 0) excl[n] = total;
}

__global__ __launch_bounds__(256) void k_fill(const int* __restrict__ src,
                                              const int* __restrict__ dst,
                                              int* __restrict__ cursor,
                                              int* __restrict__ col, int E) {
  int e = blockIdx.x * 256 + threadIdx.x;
  if (e < E) {
    int d = dst[e];
    int slot = atomicAdd(&cursor[d], 1);
    col[slot] = src[e];
  }
}

// ---------------- GEMM: C[M x 128] = A[M x 128] @ B[128 x 128] ----------------
// 128x128 tile per block, 256 threads, 8x8 microtile, K staged in chunks of 32.

#define TK 32
__global__ __launch_bounds__(256) void k_gemm(const float* __restrict__ A,
                                              const float* __restrict__ B,
                                              float* __restrict__ C, int M) {
  __shared__ float As[TK][132];  // transposed: As[k][m], pad to 132 (16B-aligned rows)
  __shared__ float Bs[TK][132];  // Bs[k][n]
  int tid = threadIdx.x;
  int m0 = blockIdx.x * 128;
  int tx = tid & 15;   // col group: cols tx*8 .. tx*8+7
  int ty = tid >> 4;   // row group: rows ty*8 .. ty*8+7
  float acc[8][8];
#pragma unroll
  for (int i = 0; i < 8; i++)
#pragma unroll
    for (int j = 0; j < 8; j++) acc[i][j] = 0.f;

  for (int kk = 0; kk < 128; kk += TK) {
    // Load A chunk: 128 rows x 32 k = 1024 float4, transpose into As[k][m]
#pragma unroll
    for (int it = 0; it < 4; it++) {
      int idx = tid + it * 256;       // 0..1023
      int r = idx >> 3;               // 0..127
      int c4 = idx & 7;               // 0..7
      int row = m0 + r;
      const float4 v = *(const float4*)&A[(size_t)(row < M ? row : 0) * 128 + kk + c4 * 4];
      As[c4 * 4 + 0][r] = v.x;
      As[c4 * 4 + 1][r] = v.y;
      As[c4 * 4 + 2][r] = v.z;
      As[c4 * 4 + 3][r] = v.w;
    }
    // Load B chunk: 32 k x 128 n = 1024 float4
#pragma unroll
    for (int it = 0; it < 4; it++) {
      int idx = tid + it * 256;
      int br = idx >> 5;              // 0..31
      int bc4 = idx & 31;             // 0..31
      const float4 v = *(const float4*)&B[(size_t)(kk + br) * 128 + bc4 * 4];
      *(float4*)&Bs[br][bc4 * 4] = v;
    }
    __syncthreads();
#pragma unroll
    for (int k = 0; k < TK; k++) {
      float a[8], b[8];
      *(float4*)&a[0] = *(const float4*)&As[k][ty * 8];
      *(float4*)&a[4] = *(const float4*)&As[k][ty * 8 + 4];
      *(float4*)&b[0] = *(const float4*)&Bs[k][tx * 8];
      *(float4*)&b[4] = *(const float4*)&Bs[k][tx * 8 + 4];
#pragma unroll
      for (int i = 0; i < 8; i++)
#pragma unroll
        for (int j = 0; j < 8; j++) acc[i][j] += a[i] * b[j];
    }
    __syncthreads();
  }
#pragma unroll
  for (int i = 0; i < 8; i++) {
    int row = m0 + ty * 8 + i;
    if (row < M) {
      float4 v0 = make_float4(acc[i][0], acc[i][1], acc[i][2], acc[i][3]);
      float4 v1 = make_float4(acc[i][4], acc[i][5], acc[i][6], acc[i][7]);
      *(float4*)&C[(size_t)row * 128 + tx * 8] = v0;
      *(float4*)&C[(size_t)row * 128 + tx * 8 + 4] = v1;
    }
  }
}

// ---------------- Aggregation: out[i] = b + dinv[i]*(dinv[i]*h[i] + sum dinv[s]*h[s]) ----

__global__ __launch_bounds__(256) void k_agg(const float* __restrict__ h,
                                             const int* __restrict__ col,
                                             const int* __restrict__ roff,
                                             const float* __restrict__ dinv,
                                             const float* __restrict__ bias,
                                             float* __restrict__ out, int N) {
  int wave = blockIdx.x * 4 + (threadIdx.x >> 6);
  int lane = threadIdx.x & 63;
  if (wave >= N) return;
  int i = wave;
  float di = dinv[i];
  float2 self = *(const float2*)&h[(size_t)i * 128 + lane * 2];
  float ax = di * self.x, ay = di * self.y;
  int s0 = roff[i], s1 = roff[i + 1];
  int j = s0;
  for (; j + 3 < s1; j += 4) {
    int sA = col[j], sB = col[j + 1], sC = col[j + 2], sD = col[j + 3];
    float wA = dinv[sA], wB = dinv[sB], wC = dinv[sC], wD = dinv[sD];
    float2 vA = *(const float2*)&h[(size_t)sA * 128 + lane * 2];
    float2 vB = *(const float2*)&h[(size_t)sB * 128 + lane * 2];
    float2 vC = *(const float2*)&h[(size_t)sC * 128 + lane * 2];
    float2 vD = *(const float2*)&h[(size_t)sD * 128 + lane * 2];
    ax += wA * vA.x + wB * vB.x + wC * vC.x + wD * vD.x;
    ay += wA * vA.y + wB * vB.y + wC * vC.y + wD * vD.y;
  }
  for (; j < s1; j++) {
    int s = col[j];
    float w = dinv[s];
    float2 v = *(const float2*)&h[(size_t)s * 128 + lane * 2];
    ax += w * v.x;
    ay += w * v.y;
  }
  float2 bb = *(const float2*)&bias[lane * 2];
  float2 o;
  o.x = di * ax + bb.x;
  o.y = di * ay + bb.y;
  *(float2*)&out[(size_t)i * 128 + lane * 2] = o;
}

// ---------------- Pooling + output head ----------------

__global__ __launch_bounds__(256) void k_gbounds(const int* __restrict__ batch,
                                                 int* __restrict__ gstart, int N, int G) {
  int g = blockIdx.x * 256 + threadIdx.x;
  if (g > G) return;
  if (g == G) { gstart[G] = N; return; }
  int lo = 0, hi = N;
  while (lo < hi) {
    int mid = (lo + hi) >> 1;
    if (batch[mid] < g) lo = mid + 1; else hi = mid;
  }
  gstart[g] = lo;
}

__global__ __launch_bounds__(128) void k_pool(const float* __restrict__ h,
                                              const int* __restrict__ gstart,
                                              float* __restrict__ pooled) {
  int g = blockIdx.x;
  int f = threadIdx.x;
  int s = gstart[g], e = gstart[g + 1];
  float acc = 0.f;
  for (int n = s; n < e; n++) acc += h[(size_t)n * 128 + f];
  float cnt = (float)(e - s);
  pooled[(size_t)g * 128 + f] = acc / fmaxf(cnt, 1.f);
}

__global__ __launch_bounds__(256) void k_final(const float* __restrict__ pooled,
                                               const float* __restrict__ W_out,
                                               const float* __restrict__ b_out,
                                               float* __restrict__ out, int G) {
  int t = blockIdx.x * 256 + threadIdx.x;
  if (t >= G * 10) return;
  int g = t / 10, o = t % 10;
  float acc = b_out[o];
  const float* pr = &pooled[(size_t)g * 128];
#pragma unroll 8
  for (int k = 0; k < 128; k++) acc += pr[k] * W_out[k * 10 + o];
  out[t] = acc;
}

// ---------------- launch ----------------

extern "C" void kernel_launch(void* const* d_in, const int* in_sizes, int n_in,
                              void* d_out, int out_size, void* d_ws, size_t ws_size,
                              hipStream_t stream) {
  const float* x     = (const float*)d_in[0];
  const int*   eidx  = (const int*)d_in[1];
  const int*   batch = (const int*)d_in[2];
  const float* W_in  = (const float*)d_in[3];
  const float* b_in  = (const float*)d_in[4];
  const float* W_hid = (const float*)d_in[5];
  const float* b_hid = (const float*)d_in[6];
  const float* W_out = (const float*)d_in[7];
  const float* b_out = (const float*)d_in[8];

  const int N = in_sizes[0] / 128;
  const int E = in_sizes[1] / 2;
  const int G = out_size / 10;

  const int* src = eidx;
  const int* dst = eidx + E;

  char* ws = (char*)d_ws;
  size_t off = 0;
  auto alloc = [&](size_t b) {
    char* p = ws + off;
    off = (off + b + 255) & ~(size_t)255;
    return p;
  };
  float* dinv   = (float*)alloc((size_t)N * 4);
  int*   counts = (int*)alloc((size_t)N * 4);
  int*   roff   = (int*)alloc((size_t)(N + 1) * 4);
  int*   cursor = (int*)alloc((size_t)N * 4);
  int*   col    = (int*)alloc((size_t)E * 4);
  float* bufA   = (float*)alloc((size_t)N * 128 * 4);
  float* bufB   = (float*)alloc((size_t)N * 128 * 4);
  int*   blksum = (int*)alloc(4096);
  int*   gstart = (int*)alloc((size_t)(G + 1) * 4);
  float* pooled = (float*)alloc((size_t)G * 128 * 4);
  (void)ws_size; (void)n_in;

  hipMemsetAsync(counts, 0, (size_t)N * 4, stream);
  k_hist<<<(E + 255) / 256, 256, 0, stream>>>(dst, counts, E);
  k_dinv<<<(N + 255) / 256, 256, 0, stream>>>(counts, dinv, N);
  int nb = (N + 1023) / 1024;
  k_scan1<<<nb, 1024, 0, stream>>>(counts, roff, blksum, N);
  k_scan2<<<1, 64, 0, stream>>>(blksum, nb);
  k_scan3<<<nb, 1024, 0, stream>>>(roff, blksum, N, E);
  hipMemcpyAsync(cursor, roff, (size_t)N * 4, hipMemcpyDeviceToDevice, stream);
  k_fill<<<(E + 255) / 256, 256, 0, stream>>>(src, dst, cursor, col, E);

  const float* hin = x;
  for (int l = 0; l < 4; l++) {
    const float* W = (l == 0) ? W_in : W_hid + (size_t)(l - 1) * 128 * 128;
    const float* b = (l == 0) ? b_in : b_hid + (size_t)(l - 1) * 128;
    k_gemm<<<(N + 127) / 128, 256, 0, stream>>>(hin, W, bufA, N);
    k_agg<<<(N + 3) / 4, 256, 0, stream>>>(bufA, col, roff, dinv, b, bufB, N);
    hin = bufB;
  }

  k_gbounds<<<(G + 1 + 255) / 256, 256, 0, stream>>>(batch, gstart, N, G);
  k_pool<<<G, 128, 0, stream>>>(bufB, gstart, pooled);
  k_final<<<(G * 10 + 255) / 256, 256, 0, stream>>>(pooled, W_out, b_out, (float*)d_out, G);
}

// Round 2
// 581.482 us; speedup vs baseline: 1.8787x; 1.8787x over previous
//
#include <hip/hip_runtime.h>

// ---------------- CSR construction ----------------

__global__ __launch_bounds__(256) void k_hist(const int* __restrict__ dst,
                                              int* __restrict__ counts, int E) {
  int e = blockIdx.x * 256 + threadIdx.x;
  if (e < E) atomicAdd(&counts[dst[e]], 1);
}

__global__ __launch_bounds__(256) void k_dinv(const int* __restrict__ counts,
                                              float* __restrict__ dinv, int N) {
  int i = blockIdx.x * 256 + threadIdx.x;
  if (i < N) dinv[i] = rsqrtf((float)(counts[i] + 1));  // +1 = self loop
}

__global__ __launch_bounds__(1024) void k_scan1(const int* __restrict__ counts,
                                                int* __restrict__ excl,
                                                int* __restrict__ blksum, int n) {
  __shared__ int s[1024];
  int tid = threadIdx.x;
  int gid = blockIdx.x * 1024 + tid;
  int v = (gid < n) ? counts[gid] : 0;
  s[tid] = v;
  __syncthreads();
  for (int off = 1; off < 1024; off <<= 1) {
    int t = (tid >= off) ? s[tid - off] : 0;
    __syncthreads();
    s[tid] += t;
    __syncthreads();
  }
  if (gid < n) excl[gid] = s[tid] - v;  // exclusive
  if (tid == 1023) blksum[blockIdx.x] = s[1023];
}

__global__ void k_scan2(int* blksum, int nb) {
  if (threadIdx.x == 0) {
    int run = 0;
    for (int i = 0; i < nb; i++) { int v = blksum[i]; blksum[i] = run; run += v; }
  }
}

__global__ __launch_bounds__(1024) void k_scan3(int* __restrict__ excl,
                                                const int* __restrict__ blksum,
                                                int n, int total) {
  int gid = blockIdx.x * 1024 + threadIdx.x;
  if (gid < n) excl[gid] += blksum[blockIdx.x];
  if (gid == 0) excl[n] = total;
}

__global__ __launch_bounds__(256) void k_fill(const int* __restrict__ src,
                                              const int* __restrict__ dst,
                                              int* __restrict__ cursor,
                                              int* __restrict__ col, int E) {
  int e = blockIdx.x * 256 + threadIdx.x;
  if (e < E) {
    int d = dst[e];
    int slot = atomicAdd(&cursor[d], 1);
    col[slot] = src[e];
  }
}

__global__ __launch_bounds__(256) void k_wv(const int* __restrict__ col,
                                            const float* __restrict__ dinv,
                                            float* __restrict__ wv, int E) {
  int e = blockIdx.x * 256 + threadIdx.x;
  if (e < E) wv[e] = dinv[col[e]];
}

// ---------------- Weight chain: Y = W_in*W1*W2*W3*W_out (128x10), c0..c3 ----------------
// Single workgroup. A/B ping-pong in LDS, padded to 16 cols.

__global__ __launch_bounds__(256) void k_wchain(const float* __restrict__ W_in,
                                                const float* __restrict__ b_in,
                                                const float* __restrict__ W_hid,
                                                const float* __restrict__ b_hid,
                                                const float* __restrict__ W_out,
                                                float* __restrict__ Y16,
                                                float* __restrict__ cvec) {
  __shared__ float A[128][16];
  __shared__ float B[128][16];
  int t = threadIdx.x;
  for (int i = t; i < 2048; i += 256) {
    int k = i >> 4, o = i & 15;
    A[k][o] = (o < 10) ? W_out[k * 10 + o] : 0.f;
  }
  __syncthreads();
  // c3 = b3^T W_out  (b3 = b_hid[2])
  if (t < 16) {
    float a = 0.f;
    for (int k = 0; k < 128; k++) a += b_hid[2 * 128 + k] * A[k][t];
    cvec[3 * 16 + t] = a;
  }

  const float* Wl[4] = {W_hid + 2 * 16384, W_hid + 1 * 16384, W_hid + 0 * 16384, W_in};
  const float* bl[3] = {b_hid + 128, b_hid + 0, b_in};
  float(*Ain)[16] = A;
  float(*Aout)[16] = B;
  for (int s = 0; s < 4; s++) {
    __syncthreads();
    for (int i = t; i < 2048; i += 256) {
      int k = i >> 4, o = i & 15;
      float acc = 0.f;
      const float* wrow = Wl[s] + (size_t)k * 128;
#pragma unroll 8
      for (int j = 0; j < 128; j++) acc += wrow[j] * Ain[j][o];
      Aout[k][o] = acc;
    }
    __syncthreads();
    if (s < 3 && t < 16) {
      float a = 0.f;
      for (int k = 0; k < 128; k++) a += bl[s][k] * Aout[k][t];
      cvec[(2 - s) * 16 + t] = a;
    }
    float(*tmp)[16] = Ain; Ain = Aout; Aout = tmp;
  }
  __syncthreads();
  for (int i = t; i < 2048; i += 256) Y16[i] = (&Ain[0][0])[i];
}

// ---------------- Z0 = X (N x 128) @ Y16 (128 x 16pad) ----------------

__global__ __launch_bounds__(256) void k_xy(const float* __restrict__ X,
                                            const float* __restrict__ Y16,
                                            float* __restrict__ Z, int N) {
  __shared__ float Xs[64][132];   // padded: rows start at distinct banks
  __shared__ float Yt[16][132];   // transposed Y: Yt[o][k]
  int t = threadIdx.x;
  for (int i = t; i < 2048; i += 256) {
    int k = i >> 4, o = i & 15;
    Yt[o][k] = Y16[k * 16 + o];
  }
  int r0 = blockIdx.x * 64;
#pragma unroll
  for (int i = 0; i < 8; i++) {
    int idx = t + i * 256;        // 0..2047 float4 slots
    int r = idx >> 5;             // 0..63
    int c4 = idx & 31;
    int row = r0 + r;
    float4 v = (row < N) ? *(const float4*)&X[(size_t)row * 128 + c4 * 4]
                         : make_float4(0.f, 0.f, 0.f, 0.f);
    *(float4*)&Xs[r][c4 * 4] = v;
  }
  __syncthreads();
  int o = t & 15, rb = t >> 4;    // rb 0..15
  float acc[4] = {0.f, 0.f, 0.f, 0.f};
  for (int k = 0; k < 128; k += 4) {
    float4 y = *(const float4*)&Yt[o][k];
#pragma unroll
    for (int i = 0; i < 4; i++) {
      float4 xv = *(const float4*)&Xs[rb + 16 * i][k];
      acc[i] += xv.x * y.x + xv.y * y.y + xv.z * y.z + xv.w * y.w;
    }
  }
#pragma unroll
  for (int i = 0; i < 4; i++) {
    int row = r0 + rb + 16 * i;
    if (row < N) Z[(size_t)row * 16 + o] = acc[i];
  }
}

// ---------------- Aggregation on 16-wide state: Z' = Â Z + c ----------------
// subwave of 16 lanes per node; 4 nodes per wave, 16 per block.

__global__ __launch_bounds__(256) void k_agg10(const float* __restrict__ Zin,
                                               const int* __restrict__ col,
                                               const float* __restrict__ wv,
                                               const int* __restrict__ roff,
                                               const float* __restrict__ dinv,
                                               const float* __restrict__ cvec,
                                               float* __restrict__ Zout, int N) {
  int node = blockIdx.x * 16 + (threadIdx.x >> 4);
  int f = threadIdx.x & 15;
  if (node >= N) return;
  float di = dinv[node];
  float acc = di * Zin[(size_t)node * 16 + f];
  int j = roff[node], e = roff[node + 1];
  for (; j + 3 < e; j += 4) {
    int s0 = col[j], s1 = col[j + 1], s2 = col[j + 2], s3 = col[j + 3];
    float w0 = wv[j], w1 = wv[j + 1], w2 = wv[j + 2], w3 = wv[j + 3];
    float v0 = Zin[(size_t)s0 * 16 + f];
    float v1 = Zin[(size_t)s1 * 16 + f];
    float v2 = Zin[(size_t)s2 * 16 + f];
    float v3 = Zin[(size_t)s3 * 16 + f];
    acc += w0 * v0 + w1 * v1 + w2 * v2 + w3 * v3;
  }
  for (; j < e; j++) acc += wv[j] * Zin[(size_t)col[j] * 16 + f];
  Zout[(size_t)node * 16 + f] = di * acc + cvec[f];
}

// ---------------- Pooling + bias ----------------

__global__ __launch_bounds__(256) void k_gbounds(const int* __restrict__ batch,
                                                 int* __restrict__ gstart, int N, int G) {
  int g = blockIdx.x * 256 + threadIdx.x;
  if (g > G) return;
  if (g == G) { gstart[G] = N; return; }
  int lo = 0, hi = N;
  while (lo < hi) {
    int mid = (lo + hi) >> 1;
    if (batch[mid] < g) lo = mid + 1; else hi = mid;
  }
  gstart[g] = lo;
}

__global__ __launch_bounds__(128) void k_pool(const float* __restrict__ Z,
                                              const int* __restrict__ gstart,
                                              const float* __restrict__ b_out,
                                              float* __restrict__ out, int G) {
  __shared__ float red[8][16];
  int g = blockIdx.x;
  int f = threadIdx.x & 15, c = threadIdx.x >> 4;  // 8 chunks
  int s = gstart[g], e = gstart[g + 1];
  float acc = 0.f;
  for (int n = s + c; n < e; n += 8) acc += Z[(size_t)n * 16 + f];
  red[c][f] = acc;
  __syncthreads();
  if (c == 0) {
    float a = 0.f;
#pragma unroll
    for (int i = 0; i < 8; i++) a += red[i][f];
    if (f < 10) out[g * 10 + f] = a / fmaxf((float)(e - s), 1.f) + b_out[f];
  }
}

// ---------------- launch ----------------

extern "C" void kernel_launch(void* const* d_in, const int* in_sizes, int n_in,
                              void* d_out, int out_size, void* d_ws, size_t ws_size,
                              hipStream_t stream) {
  const float* x     = (const float*)d_in[0];
  const int*   eidx  = (const int*)d_in[1];
  const int*   batch = (const int*)d_in[2];
  const float* W_in  = (const float*)d_in[3];
  const float* b_in  = (const float*)d_in[4];
  const float* W_hid = (const float*)d_in[5];
  const float* b_hid = (const float*)d_in[6];
  const float* W_out = (const float*)d_in[7];
  const float* b_out = (const float*)d_in[8];

  const int N = in_sizes[0] / 128;
  const int E = in_sizes[1] / 2;
  const int G = out_size / 10;

  const int* src = eidx;
  const int* dst = eidx + E;

  char* ws = (char*)d_ws;
  size_t off = 0;
  auto alloc = [&](size_t b) {
    char* p = ws + off;
    off = (off + b + 255) & ~(size_t)255;
    return p;
  };
  float* dinv   = (float*)alloc((size_t)N * 4);
  int*   counts = (int*)alloc((size_t)N * 4);
  int*   roff   = (int*)alloc((size_t)(N + 1) * 4);
  int*   cursor = (int*)alloc((size_t)N * 4);
  int*   col    = (int*)alloc((size_t)E * 4);
  float* wv     = (float*)alloc((size_t)E * 4);
  float* stateA = (float*)alloc((size_t)N * 16 * 4);
  float* stateB = (float*)alloc((size_t)N * 16 * 4);
  float* Y16    = (float*)alloc(128 * 16 * 4);
  float* cvec   = (float*)alloc(4 * 16 * 4);
  int*   blksum = (int*)alloc(4096);
  int*   gstart = (int*)alloc((size_t)(G + 1) * 4);
  (void)ws_size; (void)n_in;

  // CSR build
  hipMemsetAsync(counts, 0, (size_t)N * 4, stream);
  k_hist<<<(E + 255) / 256, 256, 0, stream>>>(dst, counts, E);
  k_dinv<<<(N + 255) / 256, 256, 0, stream>>>(counts, dinv, N);
  int nb = (N + 1023) / 1024;
  k_scan1<<<nb, 1024, 0, stream>>>(counts, roff, blksum, N);
  k_scan2<<<1, 64, 0, stream>>>(blksum, nb);
  k_scan3<<<nb, 1024, 0, stream>>>(roff, blksum, N, E);
  hipMemcpyAsync(cursor, roff, (size_t)N * 4, hipMemcpyDeviceToDevice, stream);
  k_fill<<<(E + 255) / 256, 256, 0, stream>>>(src, dst, cursor, col, E);
  k_wv<<<(E + 255) / 256, 256, 0, stream>>>(col, dinv, wv, E);

  // Weight chain (linear network collapse): Y = W_in W1 W2 W3 W_out, c0..c3
  k_wchain<<<1, 256, 0, stream>>>(W_in, b_in, W_hid, b_hid, W_out, Y16, cvec);

  // Z0 = X @ Y
  k_xy<<<(N + 63) / 64, 256, 0, stream>>>(x, Y16, stateA, N);

  // 4 aggregation passes on 10-wide (16-padded) state: Z <- Â Z + c_k
  float* zi = stateA;
  float* zo = stateB;
  for (int l = 0; l < 4; l++) {
    k_agg10<<<(N + 15) / 16, 256, 0, stream>>>(zi, col, wv, roff, dinv, cvec + 16 * l, zo, N);
    float* t = zi; zi = zo; zo = t;
  }
  // result now in zi

  k_gbounds<<<(G + 1 + 255) / 256, 256, 0, stream>>>(batch, gstart, N, G);
  k_pool<<<G, 128, 0, stream>>>(zi, gstart, b_out, (float*)d_out, G);
}

// Round 3
// 491.982 us; speedup vs baseline: 2.2204x; 1.1819x over previous
//
#include <hip/hip_runtime.h>

// ---------------- CSR construction ----------------

__global__ __launch_bounds__(256) void k_hist(const int* __restrict__ dst,
                                              int* __restrict__ counts, int E) {
  int e = blockIdx.x * 256 + threadIdx.x;
  if (e < E) atomicAdd(&counts[dst[e]], 1);
}

__global__ __launch_bounds__(256) void k_dinv(const int* __restrict__ counts,
                                              float* __restrict__ dinv, int N) {
  int i = blockIdx.x * 256 + threadIdx.x;
  if (i < N) dinv[i] = rsqrtf((float)(counts[i] + 1));  // +1 = self loop
}

__global__ __launch_bounds__(1024) void k_scan1(const int* __restrict__ counts,
                                                int* __restrict__ excl,
                                                int* __restrict__ blksum, int n) {
  __shared__ int s[1024];
  int tid = threadIdx.x;
  int gid = blockIdx.x * 1024 + tid;
  int v = (gid < n) ? counts[gid] : 0;
  s[tid] = v;
  __syncthreads();
  for (int off = 1; off < 1024; off <<= 1) {
    int t = (tid >= off) ? s[tid - off] : 0;
    __syncthreads();
    s[tid] += t;
    __syncthreads();
  }
  if (gid < n) excl[gid] = s[tid] - v;  // exclusive
  if (tid == 1023) blksum[blockIdx.x] = s[1023];
}

__global__ void k_scan2(int* blksum, int nb) {
  if (threadIdx.x == 0) {
    int run = 0;
    for (int i = 0; i < nb; i++) { int v = blksum[i]; blksum[i] = run; run += v; }
  }
}

__global__ __launch_bounds__(1024) void k_scan3(int* __restrict__ excl,
                                                const int* __restrict__ blksum,
                                                int n, int total) {
  int gid = blockIdx.x * 1024 + threadIdx.x;
  if (gid < n) excl[gid] += blksum[blockIdx.x];
  if (gid == 0) excl[n] = total;
}

// fill CSR with fused edge weight: colw[slot] = (src, dinv[src])
__global__ __launch_bounds__(256) void k_fill(const int* __restrict__ src,
                                              const int* __restrict__ dst,
                                              const float* __restrict__ dinv,
                                              int* __restrict__ cursor,
                                              int2* __restrict__ colw, int E) {
  int e = blockIdx.x * 256 + threadIdx.x;
  if (e < E) {
    int d = dst[e];
    int s = src[e];
    int slot = atomicAdd(&cursor[d], 1);
    colw[slot] = make_int2(s, __float_as_int(dinv[s]));
  }
}

// ---------------- Weight chain: Y = W_in*W1*W2*W3*W_out (128x16pad), c0..c3 ----------------
// Single workgroup, 1024 threads (16 waves on one CU for latency hiding).

__global__ __launch_bounds__(1024) void k_wchain(const float* __restrict__ W_in,
                                                 const float* __restrict__ b_in,
                                                 const float* __restrict__ W_hid,
                                                 const float* __restrict__ b_hid,
                                                 const float* __restrict__ W_out,
                                                 float* __restrict__ Y16,
                                                 float* __restrict__ cvec) {
  __shared__ float A[128][17];
  __shared__ float B[128][17];
  __shared__ float bsh[128];
  int t = threadIdx.x;
  for (int i = t; i < 2048; i += 1024) {
    int k = i >> 4, o = i & 15;
    A[k][o] = (o < 10) ? W_out[k * 10 + o] : 0.f;
  }
  if (t < 128) bsh[t] = b_hid[2 * 128 + t];
  __syncthreads();
  // c3 = b3^T W_out
  if (t < 16) {
    float a = 0.f;
    for (int k = 0; k < 128; k++) a += bsh[k] * A[k][t];
    cvec[3 * 16 + t] = a;
  }

  const float* Wl[4] = {W_hid + 2 * 16384, W_hid + 1 * 16384, W_hid + 0 * 16384, W_in};
  const float* bl[3] = {b_hid + 128, b_hid + 0, b_in};
  float(*Ain)[17] = A;
  float(*Aout)[17] = B;
  for (int s = 0; s < 4; s++) {
    __syncthreads();
    if (s < 3 && t < 128) bsh[t] = bl[s][t];
    for (int i = t; i < 2048; i += 1024) {
      int k = i >> 4, o = i & 15;
      float acc = 0.f;
      const float4* wrow = (const float4*)(Wl[s] + (size_t)k * 128);
#pragma unroll 8
      for (int j4 = 0; j4 < 32; j4++) {
        float4 w = wrow[j4];
        acc += w.x * Ain[4 * j4 + 0][o] + w.y * Ain[4 * j4 + 1][o] +
               w.z * Ain[4 * j4 + 2][o] + w.w * Ain[4 * j4 + 3][o];
      }
      Aout[k][o] = acc;
    }
    __syncthreads();
    if (s < 3 && t < 16) {
      float a = 0.f;
      for (int k = 0; k < 128; k++) a += bsh[k] * Aout[k][t];
      cvec[(2 - s) * 16 + t] = a;
    }
    float(*tmp)[17] = Ain; Ain = Aout; Aout = tmp;
  }
  __syncthreads();
  for (int i = t; i < 2048; i += 1024) {
    int k = i >> 4, o = i & 15;
    Y16[i] = Ain[k][o];
  }
}

// ---------------- Z0 = X (N x 128) @ Y16 (128 x 16pad) ----------------
// 16 lanes per node, one output column each; X row walked as float4 (broadcast).

__global__ __launch_bounds__(256) void k_xy(const float* __restrict__ X,
                                            const float* __restrict__ Y16,
                                            float* __restrict__ Z, int N) {
  __shared__ float Yt[16][132];  // Yt[o][k]
  int t = threadIdx.x;
  for (int i = t; i < 2048; i += 256) {
    int k = i >> 4, o = i & 15;
    Yt[o][k] = Y16[k * 16 + o];
  }
  __syncthreads();
  int node = blockIdx.x * 16 + (t >> 4);
  int o = t & 15;
  if (node >= N) return;
  const float4* xr = (const float4*)&X[(size_t)node * 128];
  const float4* yr = (const float4*)&Yt[o][0];
  float acc = 0.f;
#pragma unroll 4
  for (int k4 = 0; k4 < 32; k4++) {
    float4 xv = xr[k4];
    float4 y = yr[k4];
    acc += xv.x * y.x + xv.y * y.y + xv.z * y.z + xv.w * y.w;
  }
  Z[(size_t)node * 16 + o] = acc;
}

// ---------------- Aggregation on 16-wide state: Z' = Â Z + c ----------------
// 4 lanes per node (float4 each): wave gathers 16 rows x 64 B per iteration.

__global__ __launch_bounds__(256) void k_agg10(const float4* __restrict__ Zin4,
                                               const int2* __restrict__ colw,
                                               const int* __restrict__ roff,
                                               const float* __restrict__ dinv,
                                               const float* __restrict__ cvec,
                                               float4* __restrict__ Zout4, int N) {
  int node = blockIdx.x * 64 + (threadIdx.x >> 2);
  int o = threadIdx.x & 3;
  if (node >= N) return;
  float di = dinv[node];
  float4 z = Zin4[(size_t)node * 4 + o];
  float ax = di * z.x, ay = di * z.y, az = di * z.z, aw = di * z.w;
  int j = roff[node], e = roff[node + 1];
  for (; j + 1 < e; j += 2) {
    int2 c0 = colw[j], c1 = colw[j + 1];
    float w0 = __int_as_float(c0.y), w1 = __int_as_float(c1.y);
    float4 v0 = Zin4[(size_t)c0.x * 4 + o];
    float4 v1 = Zin4[(size_t)c1.x * 4 + o];
    ax += w0 * v0.x + w1 * v1.x;
    ay += w0 * v0.y + w1 * v1.y;
    az += w0 * v0.z + w1 * v1.z;
    aw += w0 * v0.w + w1 * v1.w;
  }
  if (j < e) {
    int2 c0 = colw[j];
    float w0 = __int_as_float(c0.y);
    float4 v0 = Zin4[(size_t)c0.x * 4 + o];
    ax += w0 * v0.x;
    ay += w0 * v0.y;
    az += w0 * v0.z;
    aw += w0 * v0.w;
  }
  float4 cv = ((const float4*)cvec)[o];
  float4 out;
  out.x = di * ax + cv.x;
  out.y = di * ay + cv.y;
  out.z = di * az + cv.z;
  out.w = di * aw + cv.w;
  Zout4[(size_t)node * 4 + o] = out;
}

// ---------------- Pooling + bias ----------------

__global__ __launch_bounds__(256) void k_gbounds(const int* __restrict__ batch,
                                                 int* __restrict__ gstart, int N, int G) {
  int g = blockIdx.x * 256 + threadIdx.x;
  if (g > G) return;
  if (g == G) { gstart[G] = N; return; }
  int lo = 0, hi = N;
  while (lo < hi) {
    int mid = (lo + hi) >> 1;
    if (batch[mid] < g) lo = mid + 1; else hi = mid;
  }
  gstart[g] = lo;
}

__global__ __launch_bounds__(128) void k_pool(const float* __restrict__ Z,
                                              const int* __restrict__ gstart,
                                              const float* __restrict__ b_out,
                                              float* __restrict__ out, int G) {
  __shared__ float red[8][16];
  int g = blockIdx.x;
  int f = threadIdx.x & 15, c = threadIdx.x >> 4;  // 8 chunks
  int s = gstart[g], e = gstart[g + 1];
  float acc = 0.f;
  for (int n = s + c; n < e; n += 8) acc += Z[(size_t)n * 16 + f];
  red[c][f] = acc;
  __syncthreads();
  if (c == 0) {
    float a = 0.f;
#pragma unroll
    for (int i = 0; i < 8; i++) a += red[i][f];
    if (f < 10) out[g * 10 + f] = a / fmaxf((float)(e - s), 1.f) + b_out[f];
  }
}

// ---------------- launch ----------------

extern "C" void kernel_launch(void* const* d_in, const int* in_sizes, int n_in,
                              void* d_out, int out_size, void* d_ws, size_t ws_size,
                              hipStream_t stream) {
  const float* x     = (const float*)d_in[0];
  const int*   eidx  = (const int*)d_in[1];
  const int*   batch = (const int*)d_in[2];
  const float* W_in  = (const float*)d_in[3];
  const float* b_in  = (const float*)d_in[4];
  const float* W_hid = (const float*)d_in[5];
  const float* b_hid = (const float*)d_in[6];
  const float* W_out = (const float*)d_in[7];
  const float* b_out = (const float*)d_in[8];

  const int N = in_sizes[0] / 128;
  const int E = in_sizes[1] / 2;
  const int G = out_size / 10;

  const int* src = eidx;
  const int* dst = eidx + E;

  char* ws = (char*)d_ws;
  size_t off = 0;
  auto alloc = [&](size_t b) {
    char* p = ws + off;
    off = (off + b + 255) & ~(size_t)255;
    return p;
  };
  float* dinv   = (float*)alloc((size_t)N * 4);
  int*   counts = (int*)alloc((size_t)N * 4);
  int*   roff   = (int*)alloc((size_t)(N + 1) * 4);
  int*   cursor = (int*)alloc((size_t)N * 4);
  int2*  colw   = (int2*)alloc((size_t)E * 8);
  float* stateA = (float*)alloc((size_t)N * 16 * 4);
  float* stateB = (float*)alloc((size_t)N * 16 * 4);
  float* Y16    = (float*)alloc(128 * 16 * 4);
  float* cvec   = (float*)alloc(4 * 16 * 4);
  int*   blksum = (int*)alloc(4096);
  int*   gstart = (int*)alloc((size_t)(G + 1) * 4);
  (void)ws_size; (void)n_in;

  // CSR build
  hipMemsetAsync(counts, 0, (size_t)N * 4, stream);
  k_hist<<<(E + 255) / 256, 256, 0, stream>>>(dst, counts, E);
  k_dinv<<<(N + 255) / 256, 256, 0, stream>>>(counts, dinv, N);
  int nb = (N + 1023) / 1024;
  k_scan1<<<nb, 1024, 0, stream>>>(counts, roff, blksum, N);
  k_scan2<<<1, 64, 0, stream>>>(blksum, nb);
  k_scan3<<<nb, 1024, 0, stream>>>(roff, blksum, N, E);
  hipMemcpyAsync(cursor, roff, (size_t)N * 4, hipMemcpyDeviceToDevice, stream);
  k_fill<<<(E + 255) / 256, 256, 0, stream>>>(src, dst, dinv, cursor, colw, E);

  // Weight chain (linear network collapse): Y = W_in W1 W2 W3 W_out, c0..c3
  k_wchain<<<1, 1024, 0, stream>>>(W_in, b_in, W_hid, b_hid, W_out, Y16, cvec);

  // Z0 = X @ Y
  k_xy<<<(N + 15) / 16, 256, 0, stream>>>(x, Y16, stateA, N);

  // 4 aggregation passes on 10-wide (16-padded) state: Z <- Â Z + c_k
  float* zi = stateA;
  float* zo = stateB;
  for (int l = 0; l < 4; l++) {
    k_agg10<<<(N + 63) / 64, 256, 0, stream>>>((const float4*)zi, colw, roff, dinv,
                                               cvec + 16 * l, (float4*)zo, N);
    float* t = zi; zi = zo; zo = t;
  }
  // result now in zi

  k_gbounds<<<(G + 1 + 255) / 256, 256, 0, stream>>>(batch, gstart, N, G);
  k_pool<<<G, 128, 0, stream>>>(zi, gstart, b_out, (float*)d_out, G);
}

// Round 4
// 350.640 us; speedup vs baseline: 3.1155x; 1.4031x over previous
//
#include <hip/hip_runtime.h>

#define BK_SHIFT 7
#define NB_MAX 1024
#define CHUNK 8192

// ---------------- Bucketed CSR build (no global atomics) ----------------

// Pass A: per-block bucket histogram (bucket = dst >> 7)
__global__ __launch_bounds__(256) void k_bucket_count(const int* __restrict__ dst,
                                                      int* __restrict__ blkcnt,
                                                      int E, int NB, int NBLK) {
  __shared__ int cnt[NB_MAX];
  int t = threadIdx.x, b = blockIdx.x;
  for (int i = t; i < NB; i += 256) cnt[i] = 0;
  __syncthreads();
  int e0 = b * CHUNK, e1 = min(E, e0 + CHUNK);
  for (int e = e0 + t; e < e1; e += 256) atomicAdd(&cnt[dst[e] >> BK_SHIFT], 1);
  __syncthreads();
  for (int i = t; i < NB; i += 256) blkcnt[(size_t)i * NBLK + b] = cnt[i];
}

// Pass B: per-bucket exclusive scan across blocks (in place), bucket totals out
__global__ __launch_bounds__(256) void k_bucket_scanB(int* __restrict__ blkcnt,
                                                      int* __restrict__ btot, int NBLK) {
  __shared__ int v[256];
  int t = threadIdx.x, k = blockIdx.x;
  int x = (t < NBLK) ? blkcnt[(size_t)k * NBLK + t] : 0;
  v[t] = x;
  __syncthreads();
  for (int off = 1; off < 256; off <<= 1) {
    int u = (t >= off) ? v[t - off] : 0;
    __syncthreads();
    v[t] += u;
    __syncthreads();
  }
  if (t < NBLK) blkcnt[(size_t)k * NBLK + t] = v[t] - x;  // exclusive
  if (t == 255) btot[k] = v[255];
}

// Pass B2: exclusive scan over bucket totals -> bucket base offsets
__global__ __launch_bounds__(1024) void k_bucket_base(const int* __restrict__ btot,
                                                      int* __restrict__ bbase, int NB) {
  __shared__ int v[1024];
  int t = threadIdx.x;
  int x = (t < NB) ? btot[t] : 0;
  v[t] = x;
  __syncthreads();
  for (int off = 1; off < 1024; off <<= 1) {
    int u = (t >= off) ? v[t - off] : 0;
    __syncthreads();
    v[t] += u;
    __syncthreads();
  }
  if (t < NB) bbase[t] = v[t] - x;
  if (t == 1023) bbase[NB] = v[1023];
}

// Pass C: scatter (src,dst) into bucket-contiguous staging, LDS cursors
__global__ __launch_bounds__(256) void k_bucket_scatter(const int* __restrict__ src,
                                                        const int* __restrict__ dst,
                                                        const int* __restrict__ blkoff,
                                                        const int* __restrict__ bbase,
                                                        int2* __restrict__ staging,
                                                        int E, int NB, int NBLK) {
  __shared__ int curs[NB_MAX];
  int t = threadIdx.x, b = blockIdx.x;
  for (int i = t; i < NB; i += 256) curs[i] = bbase[i] + blkoff[(size_t)i * NBLK + b];
  __syncthreads();
  int e0 = b * CHUNK, e1 = min(E, e0 + CHUNK);
  for (int e = e0 + t; e < e1; e += 256) {
    int d = dst[e], s = src[e];
    int slot = atomicAdd(&curs[d >> BK_SHIFT], 1);
    staging[slot] = make_int2(s, d);
  }
}

// Pass D: per-bucket node counts -> dinv + roff (dense), then in-bucket scatter of col
__global__ __launch_bounds__(256) void k_csr_build(const int2* __restrict__ staging,
                                                   const int* __restrict__ bbase,
                                                   int* __restrict__ roff,
                                                   float* __restrict__ dinv,
                                                   int* __restrict__ col,
                                                   int N, int NB, int E) {
  __shared__ int cnt[128];
  __shared__ int sa[128], sb[128];
  __shared__ int cursor[128];
  int t = threadIdx.x, k = blockIdx.x;
  int node0 = k << BK_SHIFT;
  int nNodes = min(128, N - node0);
  int e0 = bbase[k], e1 = bbase[k + 1];
  if (t < 128) cnt[t] = 0;
  __syncthreads();
  for (int e = e0 + t; e < e1; e += 256) atomicAdd(&cnt[staging[e].y - node0], 1);
  __syncthreads();
  int* a = sa;
  int* bq = sb;
  if (t < 128) a[t] = cnt[t];
  __syncthreads();
  for (int off = 1; off < 128; off <<= 1) {
    if (t < 128) bq[t] = (t >= off) ? a[t] + a[t - off] : a[t];
    __syncthreads();
    int* tmp = a; a = bq; bq = tmp;
  }
  if (t < 128) {
    int excl = e0 + ((t > 0) ? a[t - 1] : 0);
    cursor[t] = excl;
    if (t < nNodes) {
      roff[node0 + t] = excl;
      dinv[node0 + t] = rsqrtf((float)(cnt[t] + 1));  // +1 = self loop
    }
  }
  if (k == NB - 1 && t == 0) roff[N] = E;
  __syncthreads();
  for (int e = e0 + t; e < e1; e += 256) {
    int2 p = staging[e];
    int slot = atomicAdd(&cursor[p.y - node0], 1);
    col[slot] = p.x;
  }
}

__global__ __launch_bounds__(256) void k_wv(const int* __restrict__ col,
                                            const float* __restrict__ dinv,
                                            float* __restrict__ wv, int E) {
  int e = blockIdx.x * 256 + threadIdx.x;
  if (e < E) wv[e] = dinv[col[e]];
}

// ---------------- Weight chain: Y = W_in*W1*W2*W3*W_out (128x16pad), c0..c3 ----------------

__global__ __launch_bounds__(1024) void k_wchain(const float* __restrict__ W_in,
                                                 const float* __restrict__ b_in,
                                                 const float* __restrict__ W_hid,
                                                 const float* __restrict__ b_hid,
                                                 const float* __restrict__ W_out,
                                                 float* __restrict__ Y16,
                                                 float* __restrict__ cvec) {
  __shared__ float A[128][17];
  __shared__ float B[128][17];
  __shared__ float bsh[128];
  int t = threadIdx.x;
  for (int i = t; i < 2048; i += 1024) {
    int k = i >> 4, o = i & 15;
    A[k][o] = (o < 10) ? W_out[k * 10 + o] : 0.f;
  }
  if (t < 128) bsh[t] = b_hid[2 * 128 + t];
  __syncthreads();
  if (t < 16) {
    float a = 0.f;
    for (int k = 0; k < 128; k++) a += bsh[k] * A[k][t];
    cvec[3 * 16 + t] = a;
  }

  const float* Wl[4] = {W_hid + 2 * 16384, W_hid + 1 * 16384, W_hid + 0 * 16384, W_in};
  const float* bl[3] = {b_hid + 128, b_hid + 0, b_in};
  float(*Ain)[17] = A;
  float(*Aout)[17] = B;
  for (int s = 0; s < 4; s++) {
    __syncthreads();
    if (s < 3 && t < 128) bsh[t] = bl[s][t];
    for (int i = t; i < 2048; i += 1024) {
      int k = i >> 4, o = i & 15;
      float acc = 0.f;
      const float4* wrow = (const float4*)(Wl[s] + (size_t)k * 128);
#pragma unroll 8
      for (int j4 = 0; j4 < 32; j4++) {
        float4 w = wrow[j4];
        acc += w.x * Ain[4 * j4 + 0][o] + w.y * Ain[4 * j4 + 1][o] +
               w.z * Ain[4 * j4 + 2][o] + w.w * Ain[4 * j4 + 3][o];
      }
      Aout[k][o] = acc;
    }
    __syncthreads();
    if (s < 3 && t < 16) {
      float a = 0.f;
      for (int k = 0; k < 128; k++) a += bsh[k] * Aout[k][t];
      cvec[(2 - s) * 16 + t] = a;
    }
    float(*tmp)[17] = Ain; Ain = Aout; Aout = tmp;
  }
  __syncthreads();
  for (int i = t; i < 2048; i += 1024) {
    int k = i >> 4, o = i & 15;
    Y16[i] = Ain[k][o];
  }
}

// ---------------- Z0 = X (N x 128) @ Y16 (128 x 16pad) ----------------

__global__ __launch_bounds__(256) void k_xy(const float* __restrict__ X,
                                            const float* __restrict__ Y16,
                                            float* __restrict__ Z, int N) {
  __shared__ float Yt[16][132];  // Yt[o][k]
  int t = threadIdx.x;
  for (int i = t; i < 2048; i += 256) {
    int k = i >> 4, o = i & 15;
    Yt[o][k] = Y16[k * 16 + o];
  }
  __syncthreads();
  int node = blockIdx.x * 16 + (t >> 4);
  int o = t & 15;
  if (node >= N) return;
  const float4* xr = (const float4*)&X[(size_t)node * 128];
  const float4* yr = (const float4*)&Yt[o][0];
  float acc = 0.f;
#pragma unroll 4
  for (int k4 = 0; k4 < 32; k4++) {
    float4 xv = xr[k4];
    float4 y = yr[k4];
    acc += xv.x * y.x + xv.y * y.y + xv.z * y.z + xv.w * y.w;
  }
  Z[(size_t)node * 16 + o] = acc;
}

// ---------------- Aggregation on 16-wide state: Z' = Â Z + c ----------------
// 4 lanes per node (float4 each): wave gathers 16 rows x 64 B per iteration.

__global__ __launch_bounds__(256) void k_agg10(const float4* __restrict__ Zin4,
                                               const int* __restrict__ col,
                                               const float* __restrict__ wv,
                                               const int* __restrict__ roff,
                                               const float* __restrict__ dinv,
                                               const float* __restrict__ cvec,
                                               float4* __restrict__ Zout4, int N) {
  int node = blockIdx.x * 64 + (threadIdx.x >> 2);
  int o = threadIdx.x & 3;
  if (node >= N) return;
  float di = dinv[node];
  float4 z = Zin4[(size_t)node * 4 + o];
  float ax = di * z.x, ay = di * z.y, az = di * z.z, aw = di * z.w;
  int j = roff[node], e = roff[node + 1];
  for (; j + 3 < e; j += 4) {
    int s0 = col[j], s1 = col[j + 1], s2 = col[j + 2], s3 = col[j + 3];
    float w0 = wv[j], w1 = wv[j + 1], w2 = wv[j + 2], w3 = wv[j + 3];
    float4 v0 = Zin4[(size_t)s0 * 4 + o];
    float4 v1 = Zin4[(size_t)s1 * 4 + o];
    float4 v2 = Zin4[(size_t)s2 * 4 + o];
    float4 v3 = Zin4[(size_t)s3 * 4 + o];
    ax += w0 * v0.x + w1 * v1.x + w2 * v2.x + w3 * v3.x;
    ay += w0 * v0.y + w1 * v1.y + w2 * v2.y + w3 * v3.y;
    az += w0 * v0.z + w1 * v1.z + w2 * v2.z + w3 * v3.z;
    aw += w0 * v0.w + w1 * v1.w + w2 * v2.w + w3 * v3.w;
  }
  for (; j < e; j++) {
    int s0 = col[j];
    float w0 = wv[j];
    float4 v0 = Zin4[(size_t)s0 * 4 + o];
    ax += w0 * v0.x; ay += w0 * v0.y; az += w0 * v0.z; aw += w0 * v0.w;
  }
  float4 cv = ((const float4*)cvec)[o];
  float4 out;
  out.x = di * ax + cv.x;
  out.y = di * ay + cv.y;
  out.z = di * az + cv.z;
  out.w = di * aw + cv.w;
  Zout4[(size_t)node * 4 + o] = out;
}

// ---------------- Pooling + bias ----------------

__global__ __launch_bounds__(256) void k_gbounds(const int* __restrict__ batch,
                                                 int* __restrict__ gstart, int N, int G) {
  int g = blockIdx.x * 256 + threadIdx.x;
  if (g > G) return;
  if (g == G) { gstart[G] = N; return; }
  int lo = 0, hi = N;
  while (lo < hi) {
    int mid = (lo + hi) >> 1;
    if (batch[mid] < g) lo = mid + 1; else hi = mid;
  }
  gstart[g] = lo;
}

__global__ __launch_bounds__(128) void k_pool(const float* __restrict__ Z,
                                              const int* __restrict__ gstart,
                                              const float* __restrict__ b_out,
                                              float* __restrict__ out, int G) {
  __shared__ float red[8][16];
  int g = blockIdx.x;
  int f = threadIdx.x & 15, c = threadIdx.x >> 4;
  int s = gstart[g], e = gstart[g + 1];
  float acc = 0.f;
  for (int n = s + c; n < e; n += 8) acc += Z[(size_t)n * 16 + f];
  red[c][f] = acc;
  __syncthreads();
  if (c == 0) {
    float a = 0.f;
#pragma unroll
    for (int i = 0; i < 8; i++) a += red[i][f];
    if (f < 10) out[g * 10 + f] = a / fmaxf((float)(e - s), 1.f) + b_out[f];
  }
}

// ---------------- launch ----------------

extern "C" void kernel_launch(void* const* d_in, const int* in_sizes, int n_in,
                              void* d_out, int out_size, void* d_ws, size_t ws_size,
                              hipStream_t stream) {
  const float* x     = (const float*)d_in[0];
  const int*   eidx  = (const int*)d_in[1];
  const int*   batch = (const int*)d_in[2];
  const float* W_in  = (const float*)d_in[3];
  const float* b_in  = (const float*)d_in[4];
  const float* W_hid = (const float*)d_in[5];
  const float* b_hid = (const float*)d_in[6];
  const float* W_out = (const float*)d_in[7];
  const float* b_out = (const float*)d_in[8];

  const int N = in_sizes[0] / 128;
  const int E = in_sizes[1] / 2;
  const int G = out_size / 10;

  const int* src = eidx;
  const int* dst = eidx + E;

  const int NB = (N + 127) >> BK_SHIFT;           // node buckets (<= 1024 for N <= 131072)
  const int NBLK = (E + CHUNK - 1) / CHUNK;       // edge chunks (<= 256)

  char* ws = (char*)d_ws;
  size_t off = 0;
  auto alloc = [&](size_t b) {
    char* p = ws + off;
    off = (off + b + 255) & ~(size_t)255;
    return p;
  };
  int2*  staging = (int2*)alloc((size_t)E * 8);
  int*   col     = (int*)alloc((size_t)E * 4);
  float* wv      = (float*)alloc((size_t)E * 4);
  int*   blkcnt  = (int*)alloc((size_t)NB * NBLK * 4);
  int*   btot    = (int*)alloc((size_t)NB * 4);
  int*   bbase   = (int*)alloc((size_t)(NB + 1) * 4);
  int*   roff    = (int*)alloc((size_t)(N + 1) * 4);
  float* dinv    = (float*)alloc((size_t)N * 4);
  float* stateA  = (float*)alloc((size_t)N * 16 * 4);
  float* stateB  = (float*)alloc((size_t)N * 16 * 4);
  float* Y16     = (float*)alloc(128 * 16 * 4);
  float* cvec    = (float*)alloc(4 * 16 * 4);
  int*   gstart  = (int*)alloc((size_t)(G + 1) * 4);
  (void)ws_size; (void)n_in;

  // Bucketed CSR build (no global atomics)
  k_bucket_count<<<NBLK, 256, 0, stream>>>(dst, blkcnt, E, NB, NBLK);
  k_bucket_scanB<<<NB, 256, 0, stream>>>(blkcnt, btot, NBLK);
  k_bucket_base<<<1, 1024, 0, stream>>>(btot, bbase, NB);
  k_bucket_scatter<<<NBLK, 256, 0, stream>>>(src, dst, blkcnt, bbase, staging, E, NB, NBLK);
  k_csr_build<<<NB, 256, 0, stream>>>(staging, bbase, roff, dinv, col, N, NB, E);
  k_wv<<<(E + 255) / 256, 256, 0, stream>>>(col, dinv, wv, E);

  // Weight chain (linear network collapse): Y = W_in W1 W2 W3 W_out, c0..c3
  k_wchain<<<1, 1024, 0, stream>>>(W_in, b_in, W_hid, b_hid, W_out, Y16, cvec);

  // Z0 = X @ Y
  k_xy<<<(N + 15) / 16, 256, 0, stream>>>(x, Y16, stateA, N);

  // 4 aggregation passes on 10-wide (16-padded) state: Z <- Â Z + c_k
  float* zi = stateA;
  float* zo = stateB;
  for (int l = 0; l < 4; l++) {
    k_agg10<<<(N + 63) / 64, 256, 0, stream>>>((const float4*)zi, col, wv, roff, dinv,
                                               cvec + 16 * l, (float4*)zo, N);
    float* t = zi; zi = zo; zo = t;
  }

  k_gbounds<<<(G + 1 + 255) / 256, 256, 0, stream>>>(batch, gstart, N, G);
  k_pool<<<G, 128, 0, stream>>>(zi, gstart, b_out, (float*)d_out, G);
}

// Round 5
// 312.036 us; speedup vs baseline: 3.5009x; 1.1237x over previous
//
#include <hip/hip_runtime.h>

#define BK_SHIFT 7
#define NB_MAX 1024
#define CHUNK 8192

// ---------------- Bucketed CSR build (no global atomics) ----------------

__global__ __launch_bounds__(256) void k_bucket_count(const int* __restrict__ dst,
                                                      int* __restrict__ blkcnt,
                                                      int E, int NB, int NBLK) {
  __shared__ int cnt[NB_MAX];
  int t = threadIdx.x, b = blockIdx.x;
  for (int i = t; i < NB; i += 256) cnt[i] = 0;
  __syncthreads();
  int e0 = b * CHUNK, e1 = min(E, e0 + CHUNK);
  for (int e = e0 + t; e < e1; e += 256) atomicAdd(&cnt[dst[e] >> BK_SHIFT], 1);
  __syncthreads();
  for (int i = t; i < NB; i += 256) blkcnt[(size_t)i * NBLK + b] = cnt[i];
}

__global__ __launch_bounds__(256) void k_bucket_scanB(int* __restrict__ blkcnt,
                                                      int* __restrict__ btot, int NBLK) {
  __shared__ int v[256];
  int t = threadIdx.x, k = blockIdx.x;
  int x = (t < NBLK) ? blkcnt[(size_t)k * NBLK + t] : 0;
  v[t] = x;
  __syncthreads();
  for (int off = 1; off < 256; off <<= 1) {
    int u = (t >= off) ? v[t - off] : 0;
    __syncthreads();
    v[t] += u;
    __syncthreads();
  }
  if (t < NBLK) blkcnt[(size_t)k * NBLK + t] = v[t] - x;  // exclusive
  if (t == 255) btot[k] = v[255];
}

__global__ __launch_bounds__(1024) void k_bucket_base(const int* __restrict__ btot,
                                                      int* __restrict__ bbase, int NB) {
  __shared__ int v[1024];
  int t = threadIdx.x;
  int x = (t < NB) ? btot[t] : 0;
  v[t] = x;
  __syncthreads();
  for (int off = 1; off < 1024; off <<= 1) {
    int u = (t >= off) ? v[t - off] : 0;
    __syncthreads();
    v[t] += u;
    __syncthreads();
  }
  if (t < NB) bbase[t] = v[t] - x;
  if (t == 1023) bbase[NB] = v[1023];
}

__global__ __launch_bounds__(256) void k_bucket_scatter(const int* __restrict__ src,
                                                        const int* __restrict__ dst,
                                                        const int* __restrict__ blkoff,
                                                        const int* __restrict__ bbase,
                                                        int2* __restrict__ staging,
                                                        int E, int NB, int NBLK) {
  __shared__ int curs[NB_MAX];
  int t = threadIdx.x, b = blockIdx.x;
  for (int i = t; i < NB; i += 256) curs[i] = bbase[i] + blkoff[(size_t)i * NBLK + b];
  __syncthreads();
  int e0 = b * CHUNK, e1 = min(E, e0 + CHUNK);
  for (int e = e0 + t; e < e1; e += 256) {
    int d = dst[e], s = src[e];
    int slot = atomicAdd(&curs[d >> BK_SHIFT], 1);
    staging[slot] = make_int2(s, d);
  }
}

__global__ __launch_bounds__(256) void k_csr_build(const int2* __restrict__ staging,
                                                   const int* __restrict__ bbase,
                                                   int* __restrict__ roff,
                                                   float* __restrict__ dinv,
                                                   int* __restrict__ col,
                                                   int N, int NB, int E) {
  __shared__ int cnt[128];
  __shared__ int sa[128], sb[128];
  __shared__ int cursor[128];
  int t = threadIdx.x, k = blockIdx.x;
  int node0 = k << BK_SHIFT;
  int nNodes = min(128, N - node0);
  int e0 = bbase[k], e1 = bbase[k + 1];
  if (t < 128) cnt[t] = 0;
  __syncthreads();
  for (int e = e0 + t; e < e1; e += 256) atomicAdd(&cnt[staging[e].y - node0], 1);
  __syncthreads();
  int* a = sa;
  int* bq = sb;
  if (t < 128) a[t] = cnt[t];
  __syncthreads();
  for (int off = 1; off < 128; off <<= 1) {
    if (t < 128) bq[t] = (t >= off) ? a[t] + a[t - off] : a[t];
    __syncthreads();
    int* tmp = a; a = bq; bq = tmp;
  }
  if (t < 128) {
    int excl = e0 + ((t > 0) ? a[t - 1] : 0);
    cursor[t] = excl;
    if (t < nNodes) {
      roff[node0 + t] = excl;
      dinv[node0 + t] = rsqrtf((float)(cnt[t] + 1));  // +1 = self loop
    }
  }
  if (k == NB - 1 && t == 0) roff[N] = E;
  __syncthreads();
  for (int e = e0 + t; e < e1; e += 256) {
    int2 p = staging[e];
    int slot = atomicAdd(&cursor[p.y - node0], 1);
    col[slot] = p.x;
  }
}

// ---------------- Weight-chain stage: C(128x16) = W(128x128) @ B(128x{10|16}) ----
// 8 blocks x 256 threads. Block 0 also computes cvec_out = bias^T . B (the chain
// bias term uses the stage INPUT, which is LDS-resident here).

__global__ __launch_bounds__(256) void k_stage(const float* __restrict__ W,
                                               const float* __restrict__ Bsrc, int bcols,
                                               const float* __restrict__ bias,
                                               float* __restrict__ cvec_out,
                                               float* __restrict__ Cout) {
  __shared__ float Ws[16][129];
  __shared__ float Bs[128][17];
  int t = threadIdx.x;
  int r0 = blockIdx.x * 16;
  for (int i = t; i < 2048; i += 256) {
    int k = i >> 4, o = i & 15;
    Bs[k][o] = (o < bcols) ? Bsrc[k * bcols + o] : 0.f;
  }
  for (int i = t; i < 2048; i += 256) {
    int r = i >> 7, c = i & 127;
    Ws[r][c] = W[(size_t)(r0 + r) * 128 + c];
  }
  __syncthreads();
  if (blockIdx.x == 0 && t < 16) {
    float a = 0.f;
    for (int k = 0; k < 128; k++) a += bias[k] * Bs[k][t];
    cvec_out[t] = a;
  }
  int row = t >> 4, o = t & 15;
  float acc = 0.f;
#pragma unroll 8
  for (int k = 0; k < 128; k++) acc += Ws[row][k] * Bs[k][o];
  Cout[(size_t)(r0 + row) * 16 + o] = acc;
}

// ---------------- S0 = dinv * (X @ Y16) ----------------

__global__ __launch_bounds__(256) void k_xy(const float* __restrict__ X,
                                            const float* __restrict__ Y16,
                                            const float* __restrict__ dinv,
                                            float* __restrict__ S, int N) {
  __shared__ float Yt[16][132];  // Yt[o][k]
  int t = threadIdx.x;
  for (int i = t; i < 2048; i += 256) {
    int k = i >> 4, o = i & 15;
    Yt[o][k] = Y16[k * 16 + o];
  }
  __syncthreads();
  int node = blockIdx.x * 16 + (t >> 4);
  int o = t & 15;
  if (node >= N) return;
  const float4* xr = (const float4*)&X[(size_t)node * 128];
  const float4* yr = (const float4*)&Yt[o][0];
  float acc = 0.f;
#pragma unroll 4
  for (int k4 = 0; k4 < 32; k4++) {
    float4 xv = xr[k4];
    float4 y = yr[k4];
    acc += xv.x * y.x + xv.y * y.y + xv.z * y.z + xv.w * y.w;
  }
  S[(size_t)node * 16 + o] = acc * dinv[node];
}

// ---------------- Aggregation on scaled state ----------------
// g = (A+I).S (unweighted gather-sum); out = last ? dinv*g + c : dinv^2*g + dinv*c
// 4 lanes per node (float4 each): wave gathers 16 rows x 64 B per iteration.

__global__ __launch_bounds__(256) void k_agg10(const float4* __restrict__ Sin4,
                                               const int* __restrict__ col,
                                               const int* __restrict__ roff,
                                               const float* __restrict__ dinv,
                                               const float* __restrict__ cvec,
                                               float4* __restrict__ Sout4, int N, int last) {
  int node = blockIdx.x * 64 + (threadIdx.x >> 2);
  int o = threadIdx.x & 3;
  if (node >= N) return;
  float4 z = Sin4[(size_t)node * 4 + o];
  float ax = z.x, ay = z.y, az = z.z, aw = z.w;
  int j = roff[node], e = roff[node + 1];
  for (; j + 3 < e; j += 4) {
    int s0 = col[j], s1 = col[j + 1], s2 = col[j + 2], s3 = col[j + 3];
    float4 v0 = Sin4[(size_t)s0 * 4 + o];
    float4 v1 = Sin4[(size_t)s1 * 4 + o];
    float4 v2 = Sin4[(size_t)s2 * 4 + o];
    float4 v3 = Sin4[(size_t)s3 * 4 + o];
    ax += v0.x + v1.x + v2.x + v3.x;
    ay += v0.y + v1.y + v2.y + v3.y;
    az += v0.z + v1.z + v2.z + v3.z;
    aw += v0.w + v1.w + v2.w + v3.w;
  }
  for (; j < e; j++) {
    float4 v0 = Sin4[(size_t)col[j] * 4 + o];
    ax += v0.x; ay += v0.y; az += v0.z; aw += v0.w;
  }
  float di = dinv[node];
  float sg = last ? di : di * di;
  float sc = last ? 1.f : di;
  float4 cv = ((const float4*)cvec)[o];
  float4 out;
  out.x = sg * ax + sc * cv.x;
  out.y = sg * ay + sc * cv.y;
  out.z = sg * az + sc * cv.z;
  out.w = sg * aw + sc * cv.w;
  Sout4[(size_t)node * 4 + o] = out;
}

// ---------------- Pooling + bias ----------------

__global__ __launch_bounds__(256) void k_gbounds(const int* __restrict__ batch,
                                                 int* __restrict__ gstart, int N, int G) {
  int g = blockIdx.x * 256 + threadIdx.x;
  if (g > G) return;
  if (g == G) { gstart[G] = N; return; }
  int lo = 0, hi = N;
  while (lo < hi) {
    int mid = (lo + hi) >> 1;
    if (batch[mid] < g) lo = mid + 1; else hi = mid;
  }
  gstart[g] = lo;
}

__global__ __launch_bounds__(128) void k_pool(const float* __restrict__ Z,
                                              const int* __restrict__ gstart,
                                              const float* __restrict__ b_out,
                                              float* __restrict__ out, int G) {
  __shared__ float red[8][16];
  int g = blockIdx.x;
  int f = threadIdx.x & 15, c = threadIdx.x >> 4;
  int s = gstart[g], e = gstart[g + 1];
  float acc = 0.f;
  for (int n = s + c; n < e; n += 8) acc += Z[(size_t)n * 16 + f];
  red[c][f] = acc;
  __syncthreads();
  if (c == 0) {
    float a = 0.f;
#pragma unroll
    for (int i = 0; i < 8; i++) a += red[i][f];
    if (f < 10) out[g * 10 + f] = a / fmaxf((float)(e - s), 1.f) + b_out[f];
  }
}

// ---------------- launch ----------------

extern "C" void kernel_launch(void* const* d_in, const int* in_sizes, int n_in,
                              void* d_out, int out_size, void* d_ws, size_t ws_size,
                              hipStream_t stream) {
  const float* x     = (const float*)d_in[0];
  const int*   eidx  = (const int*)d_in[1];
  const int*   batch = (const int*)d_in[2];
  const float* W_in  = (const float*)d_in[3];
  const float* b_in  = (const float*)d_in[4];
  const float* W_hid = (const float*)d_in[5];
  const float* b_hid = (const float*)d_in[6];
  const float* W_out = (const float*)d_in[7];
  const float* b_out = (const float*)d_in[8];

  const int N = in_sizes[0] / 128;
  const int E = in_sizes[1] / 2;
  const int G = out_size / 10;

  const int* src = eidx;
  const int* dst = eidx + E;

  const int NB = (N + 127) >> BK_SHIFT;
  const int NBLK = (E + CHUNK - 1) / CHUNK;

  char* ws = (char*)d_ws;
  size_t off = 0;
  auto alloc = [&](size_t b) {
    char* p = ws + off;
    off = (off + b + 255) & ~(size_t)255;
    return p;
  };
  int2*  staging = (int2*)alloc((size_t)E * 8);
  int*   col     = (int*)alloc((size_t)E * 4);
  int*   blkcnt  = (int*)alloc((size_t)NB * NBLK * 4);
  int*   btot    = (int*)alloc((size_t)NB * 4);
  int*   bbase   = (int*)alloc((size_t)(NB + 1) * 4);
  int*   roff    = (int*)alloc((size_t)(N + 1) * 4);
  float* dinv    = (float*)alloc((size_t)N * 4);
  float* stateA  = (float*)alloc((size_t)N * 16 * 4);
  float* stateB  = (float*)alloc((size_t)N * 16 * 4);
  float* ppA     = (float*)alloc(128 * 16 * 4);
  float* ppB     = (float*)alloc(128 * 16 * 4);
  float* Y16     = (float*)alloc(128 * 16 * 4);
  float* cvec    = (float*)alloc(4 * 16 * 4);
  int*   gstart  = (int*)alloc((size_t)(G + 1) * 4);
  (void)ws_size; (void)n_in;

  // Weight chain as 4 small GEMM stages (each also emits its chain-bias term):
  // P3 = W3 @ W_out        , c3 = b3^T  W_out
  // P2 = W2 @ P3           , c2 = b2^T  P3
  // P1 = W1 @ P2           , c1 = b1^T  P2
  // Y  = W_in @ P1         , c0 = b_in^T P1
  k_stage<<<8, 256, 0, stream>>>(W_hid + 2 * 16384, W_out, 10, b_hid + 2 * 128, cvec + 48, ppA);
  k_stage<<<8, 256, 0, stream>>>(W_hid + 1 * 16384, ppA, 16, b_hid + 1 * 128, cvec + 32, ppB);
  k_stage<<<8, 256, 0, stream>>>(W_hid + 0 * 16384, ppB, 16, b_hid + 0 * 128, cvec + 16, ppA);
  k_stage<<<8, 256, 0, stream>>>(W_in, ppA, 16, b_in, cvec + 0, Y16);

  // Bucketed CSR build (no global atomics)
  k_bucket_count<<<NBLK, 256, 0, stream>>>(dst, blkcnt, E, NB, NBLK);
  k_bucket_scanB<<<NB, 256, 0, stream>>>(blkcnt, btot, NBLK);
  k_bucket_base<<<1, 1024, 0, stream>>>(btot, bbase, NB);
  k_bucket_scatter<<<NBLK, 256, 0, stream>>>(src, dst, blkcnt, bbase, staging, E, NB, NBLK);
  k_csr_build<<<NB, 256, 0, stream>>>(staging, bbase, roff, dinv, col, N, NB, E);

  // S0 = dinv * (X @ Y)
  k_xy<<<(N + 15) / 16, 256, 0, stream>>>(x, Y16, dinv, stateA, N);

  // 4 unweighted gather passes on scaled state
  float* zi = stateA;
  float* zo = stateB;
  for (int l = 0; l < 4; l++) {
    k_agg10<<<(N + 63) / 64, 256, 0, stream>>>((const float4*)zi, col, roff, dinv,
                                               cvec + 16 * l, (float4*)zo, N, (l == 3) ? 1 : 0);
    float* t = zi; zi = zo; zo = t;
  }

  k_gbounds<<<(G + 1 + 255) / 256, 256, 0, stream>>>(batch, gstart, N, G);
  k_pool<<<G, 128, 0, stream>>>(zi, gstart, b_out, (float*)d_out, G);
}

// Round 6
// 294.844 us; speedup vs baseline: 3.7050x; 1.0583x over previous
//
#include <hip/hip_runtime.h>

#define BK_SHIFT 7
#define NB_MAX 1024
#define CHUNK 8192

// ---------------- Bucketed CSR build (no global atomics) ----------------

__global__ __launch_bounds__(256) void k_bucket_count(const int* __restrict__ dst,
                                                      int* __restrict__ blkcnt,
                                                      int E, int NB, int NBLK) {
  __shared__ int cnt[NB_MAX];
  int t = threadIdx.x, b = blockIdx.x;
  for (int i = t; i < NB; i += 256) cnt[i] = 0;
  __syncthreads();
  int e0 = b * CHUNK, e1 = min(E, e0 + CHUNK);
  for (int e = e0 + t; e < e1; e += 256) atomicAdd(&cnt[dst[e] >> BK_SHIFT], 1);
  __syncthreads();
  for (int i = t; i < NB; i += 256) blkcnt[(size_t)i * NBLK + b] = cnt[i];
}

__global__ __launch_bounds__(256) void k_bucket_scanB(int* __restrict__ blkcnt,
                                                      int* __restrict__ btot, int NBLK) {
  __shared__ int v[256];
  int t = threadIdx.x, k = blockIdx.x;
  int x = (t < NBLK) ? blkcnt[(size_t)k * NBLK + t] : 0;
  v[t] = x;
  __syncthreads();
  for (int off = 1; off < 256; off <<= 1) {
    int u = (t >= off) ? v[t - off] : 0;
    __syncthreads();
    v[t] += u;
    __syncthreads();
  }
  if (t < NBLK) blkcnt[(size_t)k * NBLK + t] = v[t] - x;  // exclusive
  if (t == 255) btot[k] = v[255];
}

__global__ __launch_bounds__(1024) void k_bucket_base(const int* __restrict__ btot,
                                                      int* __restrict__ bbase, int NB) {
  __shared__ int v[1024];
  int t = threadIdx.x;
  int x = (t < NB) ? btot[t] : 0;
  v[t] = x;
  __syncthreads();
  for (int off = 1; off < 1024; off <<= 1) {
    int u = (t >= off) ? v[t - off] : 0;
    __syncthreads();
    v[t] += u;
    __syncthreads();
  }
  if (t < NB) bbase[t] = v[t] - x;
  if (t == 1023) bbase[NB] = v[1023];
}

__global__ __launch_bounds__(256) void k_bucket_scatter(const int* __restrict__ src,
                                                        const int* __restrict__ dst,
                                                        const int* __restrict__ blkoff,
                                                        const int* __restrict__ bbase,
                                                        int2* __restrict__ staging,
                                                        int E, int NB, int NBLK) {
  __shared__ int curs[NB_MAX];
  int t = threadIdx.x, b = blockIdx.x;
  for (int i = t; i < NB; i += 256) curs[i] = bbase[i] + blkoff[(size_t)i * NBLK + b];
  __syncthreads();
  int e0 = b * CHUNK, e1 = min(E, e0 + CHUNK);
  for (int e = e0 + t; e < e1; e += 256) {
    int d = dst[e], s = src[e];
    int slot = atomicAdd(&curs[d >> BK_SHIFT], 1);
    staging[slot] = make_int2(s, d);
  }
}

__global__ __launch_bounds__(256) void k_csr_build(const int2* __restrict__ staging,
                                                   const int* __restrict__ bbase,
                                                   int* __restrict__ roff,
                                                   float* __restrict__ dinv,
                                                   int* __restrict__ col,
                                                   int N, int NB, int E) {
  __shared__ int cnt[128];
  __shared__ int sa[128], sb[128];
  __shared__ int cursor[128];
  int t = threadIdx.x, k = blockIdx.x;
  int node0 = k << BK_SHIFT;
  int nNodes = min(128, N - node0);
  int e0 = bbase[k], e1 = bbase[k + 1];
  if (t < 128) cnt[t] = 0;
  __syncthreads();
  for (int e = e0 + t; e < e1; e += 256) atomicAdd(&cnt[staging[e].y - node0], 1);
  __syncthreads();
  int* a = sa;
  int* bq = sb;
  if (t < 128) a[t] = cnt[t];
  __syncthreads();
  for (int off = 1; off < 128; off <<= 1) {
    if (t < 128) bq[t] = (t >= off) ? a[t] + a[t - off] : a[t];
    __syncthreads();
    int* tmp = a; a = bq; bq = tmp;
  }
  if (t < 128) {
    int excl = e0 + ((t > 0) ? a[t - 1] : 0);
    cursor[t] = excl;
    if (t < nNodes) {
      roff[node0 + t] = excl;
      dinv[node0 + t] = rsqrtf((float)(cnt[t] + 1));  // +1 = self loop
    }
  }
  if (k == NB - 1 && t == 0) roff[N] = E;
  __syncthreads();
  for (int e = e0 + t; e < e1; e += 256) {
    int2 p = staging[e];
    int slot = atomicAdd(&cursor[p.y - node0], 1);
    col[slot] = p.x;
  }
}

// ---------------- Weight-chain stage: C(128x16) = W(128x128) @ B(128x{10|16}) ----

__global__ __launch_bounds__(256) void k_stage(const float* __restrict__ W,
                                               const float* __restrict__ Bsrc, int bcols,
                                               const float* __restrict__ bias,
                                               float* __restrict__ cvec_out,
                                               float* __restrict__ Cout) {
  __shared__ float Ws[16][129];
  __shared__ float Bs[128][17];
  int t = threadIdx.x;
  int r0 = blockIdx.x * 16;
  for (int i = t; i < 2048; i += 256) {
    int k = i >> 4, o = i & 15;
    Bs[k][o] = (o < bcols) ? Bsrc[k * bcols + o] : 0.f;
  }
  for (int i = t; i < 2048; i += 256) {
    int r = i >> 7, c = i & 127;
    Ws[r][c] = W[(size_t)(r0 + r) * 128 + c];
  }
  __syncthreads();
  if (blockIdx.x == 0 && t < 16) {
    float a = 0.f;
    for (int k = 0; k < 128; k++) a += bias[k] * Bs[k][t];
    cvec_out[t] = a;
  }
  int row = t >> 4, o = t & 15;
  float acc = 0.f;
#pragma unroll 8
  for (int k = 0; k < 128; k++) acc += Ws[row][k] * Bs[k][o];
  Cout[(size_t)(r0 + row) * 16 + o] = acc;
}

// ---------------- S0 = dinv * (X @ Y16): LDS-tiled skinny GEMM ----------------
// 128 nodes/block, 256 threads. Thread microtile: 4 nodes x 2 cols.
// X tile staged via fully-coalesced float4; 6 ds_read_b128 per 32 FMA.

__global__ __launch_bounds__(256) void k_xy(const float* __restrict__ X,
                                            const float* __restrict__ Y16,
                                            const float* __restrict__ dinv,
                                            float* __restrict__ S, int N) {
  __shared__ float Xs[128][132];
  __shared__ float Yt[16][132];  // Yt[o][k]
  int t = threadIdx.x;
  int n0 = blockIdx.x * 128;
  for (int i = t; i < 2048; i += 256) {
    int k = i >> 4, o = i & 15;
    Yt[o][k] = Y16[k * 16 + o];
  }
#pragma unroll
  for (int it = 0; it < 16; it++) {
    int idx = t + it * 256;        // 0..4095 float4 slots
    int r = idx >> 5;              // 0..127
    int c4 = idx & 31;
    int row = n0 + r;
    float4 v = *(const float4*)&X[(size_t)(row < N ? row : 0) * 128 + c4 * 4];
    *(float4*)&Xs[r][c4 * 4] = v;
  }
  __syncthreads();
  int cp = t & 7;                  // col pair: cols 2cp, 2cp+1
  int q = t >> 3;                  // 0..31 -> nodes q, q+32, q+64, q+96
  float acc[4][2];
#pragma unroll
  for (int i = 0; i < 4; i++) { acc[i][0] = 0.f; acc[i][1] = 0.f; }
  const float4* y0r = (const float4*)&Yt[2 * cp][0];
  const float4* y1r = (const float4*)&Yt[2 * cp + 1][0];
#pragma unroll 4
  for (int k4 = 0; k4 < 32; k4++) {
    float4 y0 = y0r[k4];
    float4 y1 = y1r[k4];
#pragma unroll
    for (int i = 0; i < 4; i++) {
      float4 xv = *(const float4*)&Xs[q + 32 * i][k4 * 4];
      acc[i][0] += xv.x * y0.x + xv.y * y0.y + xv.z * y0.z + xv.w * y0.w;
      acc[i][1] += xv.x * y1.x + xv.y * y1.y + xv.z * y1.z + xv.w * y1.w;
    }
  }
#pragma unroll
  for (int i = 0; i < 4; i++) {
    int node = n0 + q + 32 * i;
    if (node < N) {
      float di = dinv[node];
      float2 o2 = make_float2(acc[i][0] * di, acc[i][1] * di);
      *(float2*)&S[(size_t)node * 16 + 2 * cp] = o2;
    }
  }
}

// ---------------- Aggregation on scaled state ----------------
// g = (A+I).S (unweighted gather-sum); out = last ? dinv*g + c : dinv^2*g + dinv*c

__global__ __launch_bounds__(256) void k_agg10(const float4* __restrict__ Sin4,
                                               const int* __restrict__ col,
                                               const int* __restrict__ roff,
                                               const float* __restrict__ dinv,
                                               const float* __restrict__ cvec,
                                               float4* __restrict__ Sout4, int N, int last) {
  int node = blockIdx.x * 64 + (threadIdx.x >> 2);
  int o = threadIdx.x & 3;
  if (node >= N) return;
  float4 z = Sin4[(size_t)node * 4 + o];
  float ax = z.x, ay = z.y, az = z.z, aw = z.w;
  int j = roff[node], e = roff[node + 1];
  for (; j + 3 < e; j += 4) {
    int s0 = col[j], s1 = col[j + 1], s2 = col[j + 2], s3 = col[j + 3];
    float4 v0 = Sin4[(size_t)s0 * 4 + o];
    float4 v1 = Sin4[(size_t)s1 * 4 + o];
    float4 v2 = Sin4[(size_t)s2 * 4 + o];
    float4 v3 = Sin4[(size_t)s3 * 4 + o];
    ax += v0.x + v1.x + v2.x + v3.x;
    ay += v0.y + v1.y + v2.y + v3.y;
    az += v0.z + v1.z + v2.z + v3.z;
    aw += v0.w + v1.w + v2.w + v3.w;
  }
  for (; j < e; j++) {
    float4 v0 = Sin4[(size_t)col[j] * 4 + o];
    ax += v0.x; ay += v0.y; az += v0.z; aw += v0.w;
  }
  float di = dinv[node];
  float sg = last ? di : di * di;
  float sc = last ? 1.f : di;
  float4 cv = ((const float4*)cvec)[o];
  float4 out;
  out.x = sg * ax + sc * cv.x;
  out.y = sg * ay + sc * cv.y;
  out.z = sg * az + sc * cv.z;
  out.w = sg * aw + sc * cv.w;
  Sout4[(size_t)node * 4 + o] = out;
}

// ---------------- Pooling + bias ----------------

__global__ __launch_bounds__(256) void k_gbounds(const int* __restrict__ batch,
                                                 int* __restrict__ gstart, int N, int G) {
  int g = blockIdx.x * 256 + threadIdx.x;
  if (g > G) return;
  if (g == G) { gstart[G] = N; return; }
  int lo = 0, hi = N;
  while (lo < hi) {
    int mid = (lo + hi) >> 1;
    if (batch[mid] < g) lo = mid + 1; else hi = mid;
  }
  gstart[g] = lo;
}

__global__ __launch_bounds__(128) void k_pool(const float* __restrict__ Z,
                                              const int* __restrict__ gstart,
                                              const float* __restrict__ b_out,
                                              float* __restrict__ out, int G) {
  __shared__ float red[8][16];
  int g = blockIdx.x;
  int f = threadIdx.x & 15, c = threadIdx.x >> 4;
  int s = gstart[g], e = gstart[g + 1];
  float acc = 0.f;
  for (int n = s + c; n < e; n += 8) acc += Z[(size_t)n * 16 + f];
  red[c][f] = acc;
  __syncthreads();
  if (c == 0) {
    float a = 0.f;
#pragma unroll
    for (int i = 0; i < 8; i++) a += red[i][f];
    if (f < 10) out[g * 10 + f] = a / fmaxf((float)(e - s), 1.f) + b_out[f];
  }
}

// ---------------- launch ----------------

extern "C" void kernel_launch(void* const* d_in, const int* in_sizes, int n_in,
                              void* d_out, int out_size, void* d_ws, size_t ws_size,
                              hipStream_t stream) {
  const float* x     = (const float*)d_in[0];
  const int*   eidx  = (const int*)d_in[1];
  const int*   batch = (const int*)d_in[2];
  const float* W_in  = (const float*)d_in[3];
  const float* b_in  = (const float*)d_in[4];
  const float* W_hid = (const float*)d_in[5];
  const float* b_hid = (const float*)d_in[6];
  const float* W_out = (const float*)d_in[7];
  const float* b_out = (const float*)d_in[8];

  const int N = in_sizes[0] / 128;
  const int E = in_sizes[1] / 2;
  const int G = out_size / 10;

  const int* src = eidx;
  const int* dst = eidx + E;

  const int NB = (N + 127) >> BK_SHIFT;
  const int NBLK = (E + CHUNK - 1) / CHUNK;

  char* ws = (char*)d_ws;
  size_t off = 0;
  auto alloc = [&](size_t b) {
    char* p = ws + off;
    off = (off + b + 255) & ~(size_t)255;
    return p;
  };
  int2*  staging = (int2*)alloc((size_t)E * 8);
  int*   col     = (int*)alloc((size_t)E * 4);
  int*   blkcnt  = (int*)alloc((size_t)NB * NBLK * 4);
  int*   btot    = (int*)alloc((size_t)NB * 4);
  int*   bbase   = (int*)alloc((size_t)(NB + 1) * 4);
  int*   roff    = (int*)alloc((size_t)(N + 1) * 4);
  float* dinv    = (float*)alloc((size_t)N * 4);
  float* stateA  = (float*)alloc((size_t)N * 16 * 4);
  float* stateB  = (float*)alloc((size_t)N * 16 * 4);
  float* ppA     = (float*)alloc(128 * 16 * 4);
  float* ppB     = (float*)alloc(128 * 16 * 4);
  float* Y16     = (float*)alloc(128 * 16 * 4);
  float* cvec    = (float*)alloc(4 * 16 * 4);
  int*   gstart  = (int*)alloc((size_t)(G + 1) * 4);
  (void)ws_size; (void)n_in;

  // Weight chain as 4 small GEMM stages (each also emits its chain-bias term)
  k_stage<<<8, 256, 0, stream>>>(W_hid + 2 * 16384, W_out, 10, b_hid + 2 * 128, cvec + 48, ppA);
  k_stage<<<8, 256, 0, stream>>>(W_hid + 1 * 16384, ppA, 16, b_hid + 1 * 128, cvec + 32, ppB);
  k_stage<<<8, 256, 0, stream>>>(W_hid + 0 * 16384, ppB, 16, b_hid + 0 * 128, cvec + 16, ppA);
  k_stage<<<8, 256, 0, stream>>>(W_in, ppA, 16, b_in, cvec + 0, Y16);

  // Bucketed CSR build (no global atomics)
  k_bucket_count<<<NBLK, 256, 0, stream>>>(dst, blkcnt, E, NB, NBLK);
  k_bucket_scanB<<<NB, 256, 0, stream>>>(blkcnt, btot, NBLK);
  k_bucket_base<<<1, 1024, 0, stream>>>(btot, bbase, NB);
  k_bucket_scatter<<<NBLK, 256, 0, stream>>>(src, dst, blkcnt, bbase, staging, E, NB, NBLK);
  k_csr_build<<<NB, 256, 0, stream>>>(staging, bbase, roff, dinv, col, N, NB, E);

  // S0 = dinv * (X @ Y)
  k_xy<<<(N + 127) / 128, 256, 0, stream>>>(x, Y16, dinv, stateA, N);

  // 4 unweighted gather passes on scaled state
  float* zi = stateA;
  float* zo = stateB;
  for (int l = 0; l < 4; l++) {
    k_agg10<<<(N + 63) / 64, 256, 0, stream>>>((const float4*)zi, col, roff, dinv,
                                               cvec + 16 * l, (float4*)zo, N, (l == 3) ? 1 : 0);
    float* t = zi; zi = zo; zo = t;
  }

  k_gbounds<<<(G + 1 + 255) / 256, 256, 0, stream>>>(batch, gstart, N, G);
  k_pool<<<G, 128, 0, stream>>>(zi, gstart, b_out, (float*)d_out, G);
}